// Round 11
// baseline (27.772 us; speedup 1.0000x reference)
//
#include <hip/hip_runtime.h>

#define HH 2048
#define WW 2048
#define OH 512
#define OW 512
#define NBLK 1536          // one 32x16-output tile per block: 3ch * 16tcc * 32trr

__device__ __forceinline__ float rfl(float v) {
    return __int_as_float(__builtin_amdgcn_readfirstlane(__float_as_int(v)));
}

// No LDS, no barriers: input (50 MB) is L2/L3-resident in steady state; each
// thread gathers its 12x10 window via three 16B-aligned dwordx4 per row.
// Occupancy 6 waves/SIMD; waves free-run (no phase-locking).
__global__ __launch_bounds__(512, 6)
void wpt2_kernel(const float* __restrict__ x,
                 const float* __restrict__ dec_lo,
                 const float* __restrict__ dec_hi,
                 float* __restrict__ out) {
    const int tx  = threadIdx.x;          // 0..31 -> output col
    const int ty  = threadIdx.y;          // 0..15 -> output row

    // bijective XCD swizzle (1536 % 8 == 0): 192 consecutive tiles per XCD
    const int bid = blockIdx.x;
    const int t   = (bid & 7) * (NBLK / 8) + (bid >> 3);
    const int ch  = t >> 9;               // 0..2
    const int tcc = (t & 511) >> 5;       // 0..15
    const int trr = t & 31;               // 0..31  (innermost: vertical L2 reuse)

    // ---- composed 10-tap filters (graycode band order), pinned to SGPRs ----
    float lo[4], hi[4];
#pragma unroll
    for (int j = 0; j < 4; ++j) { lo[j] = dec_lo[j]; hi[j] = dec_hi[j]; }
    float F[4][10];
#pragma unroll
    for (int g = 0; g < 4; ++g) {
        const float* f1 = (g >= 2) ? hi : lo;             // level-1: 0,0,1,1
        const float* f2 = (g == 1 || g == 2) ? hi : lo;   // level-2: 0,1,1,0
#pragma unroll
        for (int d = 0; d < 10; ++d) F[g][d] = 0.f;
#pragma unroll
        for (int j2 = 0; j2 < 4; ++j2)
#pragma unroll
            for (int j1 = 0; j1 < 4; ++j1)
                F[g][2 * j2 + j1] = fmaf(f2[j2], f1[j1], F[g][2 * j2 + j1]);
    }
#pragma unroll
    for (int g = 0; g < 4; ++g)
#pragma unroll
        for (int d = 0; d < 10; ++d) F[g][d] = rfl(F[g][d]);

    const float* xc = x + (size_t)ch * HH * WW;
    const int kr = 16 * trr + ty;
    const int kc = 32 * tcc + tx;

    // three 16B-aligned column chunks covering cols [4kc-8, 4kc+3];
    // wrap each chunk independently (only kc<=1 wraps; chunk stays in-row)
    int c0 = 4 * kc - 8;
    int c1 = 4 * kc - 4;
    const int c2 = 4 * kc;
    if (c0 < 0) c0 += WW;
    if (c1 < 0) c1 += WW;
    const int r0 = 4 * kr - 6;

    // ---- row pass: 10 rows, direct global gather ----
    float tacc[4][10];
#pragma unroll
    for (int g = 0; g < 4; ++g)
#pragma unroll
        for (int d = 0; d < 10; ++d) tacc[g][d] = 0.f;

#pragma unroll
    for (int u = 0; u < 10; ++u) {
        int r = r0 + u;  if (r < 0) r += HH;      // negative wrap only
        const float* rp = xc + (size_t)r * WW;
        const float4 a = *reinterpret_cast<const float4*>(rp + c0);
        const float4 b = *reinterpret_cast<const float4*>(rp + c1);
        const float4 c = *reinterpret_cast<const float4*>(rp + c2);
        // row[i] = global col (4kc-8+i); needed col for dc: 4kc+3-dc = row[11-dc]
        const float row[12] = {a.x, a.y, a.z, a.w, b.x, b.y, b.z, b.w,
                               c.x, c.y, c.z, c.w};
        const int dr = 9 - u;
#pragma unroll
        for (int dc = 0; dc < 10; ++dc) {
            const float v = row[11 - dc];
#pragma unroll
            for (int g = 0; g < 4; ++g)
                tacc[g][dc] = fmaf(F[g][dr], v, tacc[g][dc]);
        }
    }

    // ---- column combine + 16 nontemporal stores ----
    const size_t plane = (size_t)OH * OW;
    float* op = out + (size_t)(ch * 16) * plane + (size_t)kr * OW + kc;
#pragma unroll
    for (int gi = 0; gi < 4; ++gi) {
#pragma unroll
        for (int gj = 0; gj < 4; ++gj) {
            float acc = 0.f;
#pragma unroll
            for (int dc = 0; dc < 10; ++dc)
                acc = fmaf(F[gj][dc], tacc[gi][dc], acc);
            __builtin_nontemporal_store(acc, op + (size_t)(gi * 4 + gj) * plane);
        }
    }
}

extern "C" void kernel_launch(void* const* d_in, const int* in_sizes, int n_in,
                              void* d_out, int out_size, void* d_ws, size_t ws_size,
                              hipStream_t stream) {
    const float* x      = (const float*)d_in[0];
    const float* dec_lo = (const float*)d_in[1];
    const float* dec_hi = (const float*)d_in[2];
    float* out          = (float*)d_out;

    hipLaunchKernelGGL(wpt2_kernel, dim3(NBLK), dim3(32, 16), 0, stream,
                       x, dec_lo, dec_hi, out);
}